// Round 3
// baseline (1208.085 us; speedup 1.0000x reference)
//
#include <hip/hip_runtime.h>
#include <cstdint>
#include <cstddef>

// BooleanReservoir — persistent kernel, v6.
// lane = batch; states[node] = u64 (bit b = batch b).
// R7 structural change: NO grid barrier. Per-step state buffers st[0..128]
// (no WAR hazards; u(t) rows + no-neigh/dummy values pre-materialized for all
// t by pre-kernels) + per-block monotone progress flags (x4 replicas against
// hot lines). Per block each step: compute -> __syncthreads (drains vmcnt) ->
// store flag=t+1 -> watcher wave polls all 512 flags directly (64 lanes x 4
// u64 loads = full coverage per round) -> LDS broadcast -> waves proceed.
// Removes the leader-observe + go-store + spinner-observe legs (~2 fabric RTTs
// per step) of the old two-sided barrier. Substrate reverted to the faster v4
// config (512 blocks x 512 thr, 1 gather/wave).

#define N_NODES   20000
#define N_INPUT   64
#define K_MAX     12
#define T_STEPS   128
#define N_BATCH   64
#define N_OUT     10
#define N_FEAT    (N_NODES - N_INPUT)   // 19936
#define DUMMY_NODE 20000                // always-zero state word
#define ST_WORDS  20004
#define T_BUF     (T_STEPS + 1)         // st[0..128]

#define NBLK 512
#define NTHR 512                        // 8 waves/block, 2 blocks/CU
#define NPB  39                         // 512*39 = 19968 >= 19936
#define NPB_PAD 40                      // 8 waves * 5 nodes
#define WATCH_WAVE 7
#define FL_REP 4                        // flag replicas (hot-line spreading)
#define FL_STRIDE 1024                  // u32 per replica (4 KB apart)
#define PL_FILL 39                      // fill blocks inside pack_lut grid
#define PL_LUT  2500
#define PL_TOT  (PL_FILL + PL_LUT)

typedef unsigned long long u64;

// ---------------- pack x: xp[t][b] = bits j of x[b][t][j] ----------------
__global__ __launch_bounds__(256) void pack_x_kernel(const int* __restrict__ x,
                                                     u64* __restrict__ xp) {
  const int t = blockIdx.x;
  const int wave = threadIdx.x >> 6, lane = threadIdx.x & 63;
  for (int b = wave; b < N_BATCH; b += 4) {
    int v = x[((size_t)b * T_STEPS + t) * 64 + lane];
    u64 bal = __ballot(v != 0);
    if (lane == 0) xp[(size_t)t * N_BATCH + b] = bal;
  }
}

// ---- pack lut (full-machine stream) + pre-fill all 129 state buffers ----
// fill: st[t][n] = init word for every t and every n>=64 (incl dummy/pad = 0).
// Nodes with neighbors get overwritten by producers before any consumer reads
// (flag protocol); no-neigh nodes keep this value forever — correct by design.
__global__ __launch_bounds__(512) void pack_lut_fill_kernel(
    const int* __restrict__ lut, const int* __restrict__ inis,
    u64* __restrict__ lutp, u64* __restrict__ st_all) {
  if (blockIdx.x < PL_FILL) {
    int n = N_INPUT + blockIdx.x * 512 + threadIdx.x;   // [64, 20032)
    if (n < ST_WORDS) {
      u64 w = (n < N_NODES && inis[n] != 0) ? ~0ull : 0ull;
      for (int t = 0; t < T_BUF; t++)                   // lane-coalesced 512 B
        st_all[(size_t)t * ST_WORDS + n] = w;
    }
  } else {
    const int wave = threadIdx.x >> 6, lane = threadIdx.x & 63;
    const int nwords = N_NODES * 64;                    // 1,280,000
    for (int widx = (blockIdx.x - PL_FILL) * 8 + wave; widx < nwords;
         widx += PL_LUT * 8) {
      int v = lut[(size_t)widx * 64 + lane];            // coalesced 256 B
      u64 bal = __ballot(v != 0);
      if (lane == 0) lutp[widx] = bal;
    }
  }
}

// -------- init: wcol (input weight columns) + zero flag replicas --------
__global__ __launch_bounds__(256) void init_kernel(const int* __restrict__ w_in,
                                                   u64* __restrict__ wcol,
                                                   unsigned* __restrict__ fl) {
  if (blockIdx.x == 0) {
    const int wave = threadIdx.x >> 6, lane = threadIdx.x & 63;
    for (int i = wave; i < 64; i += 4) {
      int wv = w_in[(size_t)lane * 64 + i];  // lane = j
      u64 wc = __ballot(wv != 0);
      if (lane == 0) wcol[i] = wc;
    }
  } else {
    for (int k = threadIdx.x; k < FL_REP * FL_STRIDE; k += 256)
      fl[k] = 0u;                            // ws re-poisoned each call
  }
}

// -------- u(t) for all t, written DIRECTLY into st[t][0..63] --------
__global__ __launch_bounds__(64) void u_pre_kernel(const u64* __restrict__ xp,
                                                   const u64* __restrict__ wcol,
                                                   u64* __restrict__ st_all) {
  const int t = blockIdx.x, lane = threadIdx.x;
  u64 xw = xp[(size_t)t * N_BATCH + lane];   // lane = batch
  for (int i = 0; i < 64; i++) {
    u64 ub = __ballot((xw & wcol[i]) != 0);
    if (lane == 0) st_all[(size_t)t * ST_WORDS + i] = ub;
  }
}

// ---- 64x64 bit transpose: lane l holds row l; returns lane b holding column b ----
__device__ __forceinline__ u64 bit_transpose64(u64 w, int lane) {
  const u64 LO0 = 0x00000000FFFFFFFFull, LO1 = 0x0000FFFF0000FFFFull,
            LO2 = 0x00FF00FF00FF00FFull, LO3 = 0x0F0F0F0F0F0F0F0Full,
            LO4 = 0x3333333333333333ull, LO5 = 0x5555555555555555ull;
#define XP_STAGE(d, LO)                                                  \
  {                                                                      \
    u64 p = (u64)__shfl_xor((long long)w, (d), 64);                      \
    if (lane & (d)) w = ((p >> (d)) & (LO)) | (w & ~(LO));               \
    else            w = (w & (LO)) | ((p << (d)) & ~(LO));               \
  }
  XP_STAGE(32, LO0) XP_STAGE(16, LO1) XP_STAGE(8, LO2)
  XP_STAGE(4,  LO3) XP_STAGE(2,  LO4) XP_STAGE(1, LO5)
#undef XP_STAGE
  return w;
}

// ---------------- persistent reservoir: all 128 steps, no barrier ----------------
__global__ __launch_bounds__(NTHR, 4) void reservoir_kernel(
    const u64* __restrict__ lutp, const int* __restrict__ adj,
    const int* __restrict__ mask, u64* __restrict__ st_all,
    unsigned* __restrict__ fl) {
  __shared__ u64 lut_lds[NPB_PAD * 64];        // 20480 B
  __shared__ int adj_lds[NPB_PAD * K_MAX];     //  1920 B
  __shared__ unsigned char hn_lds[NPB_PAD];
  __shared__ int avail_lds;

  const int bi = blockIdx.x;
  const int tid = threadIdx.x;
  const int wave = tid >> 6, lane = tid & 63;
  const int base = N_INPUT + bi * NPB;
  const int nloc = min(NPB, N_NODES - base);   // last block: 7

  if (tid == 0) avail_lds = 0;

  // ---- prologue: adjacency (slot-REVERSED: slot j at offset 11-j) + hn ----
  if (tid < NPB_PAD) {
    int i = tid, h = 0;
    if (i < nloc) {
      for (int j = 0; j < K_MAX; j++) {
        int m = mask[(size_t)(base + i) * K_MAX + j];
        int a = adj[(size_t)(base + i) * K_MAX + j];
        adj_lds[i * K_MAX + (K_MAX - 1 - j)] = m ? a : DUMMY_NODE;
        h |= m;
      }
    } else {
      for (int j = 0; j < K_MAX; j++) adj_lds[i * K_MAX + j] = DUMMY_NODE;
    }
    hn_lds[i] = (unsigned char)(h ? 1 : 0);
  }

  // ---- prologue: stage pre-packed LUT slice (contiguous ~20 KB) ----
  const u64* lp = lutp + (size_t)base * 64;
  const int nwords = nloc * 64;
  for (int idx = tid; idx < nwords; idx += NTHR)
    lut_lds[idx] = lp[idx];
  __syncthreads();

  const int l0 = wave * 5;
  const int cnt = min(5, nloc - l0);           // may be <= 0

  int a0 = DUMMY_NODE;                         // lanes 60-63 gather the 0-word
  if (lane < 60) a0 = adj_lds[l0 * K_MAX + lane];
  unsigned hmask = 0;
#pragma unroll
  for (int i = 0; i < 5; i++) hmask |= (unsigned)hn_lds[l0 + i] << i;

  // this block's flag replica (consumer side)
  const u64* fp = (const u64*)(fl + (size_t)(bi & (FL_REP - 1)) * FL_STRIDE);

  for (int t = 0; t < T_STEPS; t++) {
    // ---- wait: st[t] ready = all 512 block flags >= t ----
    if (t) {
      if (wave == WATCH_WAVE) {
        const unsigned tgt = (unsigned)t;
        for (;;) {
          u64 f0 = __hip_atomic_load(&fp[lane],       __ATOMIC_RELAXED, __HIP_MEMORY_SCOPE_AGENT);
          u64 f1 = __hip_atomic_load(&fp[64 + lane],  __ATOMIC_RELAXED, __HIP_MEMORY_SCOPE_AGENT);
          u64 f2 = __hip_atomic_load(&fp[128 + lane], __ATOMIC_RELAXED, __HIP_MEMORY_SCOPE_AGENT);
          u64 f3 = __hip_atomic_load(&fp[192 + lane], __ATOMIC_RELAXED, __HIP_MEMORY_SCOPE_AGENT);
          bool ok = (unsigned)f0 >= tgt && (unsigned)(f0 >> 32) >= tgt &&
                    (unsigned)f1 >= tgt && (unsigned)(f1 >> 32) >= tgt &&
                    (unsigned)f2 >= tgt && (unsigned)(f2 >> 32) >= tgt &&
                    (unsigned)f3 >= tgt && (unsigned)(f3 >> 32) >= tgt;
          if (__all(ok)) break;
        }
        __builtin_amdgcn_fence(__ATOMIC_ACQUIRE, "workgroup");  // compiler ordering
        if (lane == 0)
          __hip_atomic_store(&avail_lds, t, __ATOMIC_RELAXED, __HIP_MEMORY_SCOPE_WORKGROUP);
      } else {
        while (__hip_atomic_load(&avail_lds, __ATOMIC_RELAXED, __HIP_MEMORY_SCOPE_WORKGROUP) < t) {}
        __builtin_amdgcn_fence(__ATOMIC_ACQUIRE, "workgroup");  // compiler ordering
      }
    }

    const u64* stc = st_all + (size_t)t * ST_WORDS;
    u64* stn = st_all + (size_t)(t + 1) * ST_WORDS;

    // gather + transpose: lane b holds all 60 index bits for batch b
    u64 w = __hip_atomic_load(&stc[a0], __ATOMIC_RELAXED, __HIP_MEMORY_SCOPE_AGENT);
    w = bit_transpose64(w, lane);

#pragma unroll
    for (int i = 0; i < 5; i++) {
      if (i < cnt) {                           // wave-uniform
        unsigned idx = (unsigned)(w >> (12 * i)) & 0xFFFu;   // MSB-first index
        u64 g = lut_lds[(l0 + i) * 64 + (idx >> 6)];
        u64 res = __ballot((g >> (idx & 63)) & 1ull);
        if (lane == 0 && ((hmask >> i) & 1u))
          __hip_atomic_store(&stn[base + l0 + i], res,
                             __ATOMIC_RELAXED, __HIP_MEMORY_SCOPE_AGENT);
      }
    }

    // ---- publish: flag = t+1 after all block stores drained ----
    if (t != T_STEPS - 1) {
      __syncthreads();   // each wave drains its vmcnt: stores are at L3
      __builtin_amdgcn_fence(__ATOMIC_RELEASE, "workgroup");  // compiler ordering
      if (tid < FL_REP)
        __hip_atomic_store(&fl[tid * FL_STRIDE + bi], (unsigned)(t + 1),
                           __ATOMIC_RELAXED, __HIP_MEMORY_SCOPE_AGENT);
    }
  }
}

// ---------------- readout: sigmoid(feats @ W_out^T + b_out) ----------------
__global__ __launch_bounds__(256) void readout_kernel(const u64* __restrict__ st,
                                                      const float* __restrict__ Wout,
                                                      const float* __restrict__ bout,
                                                      float* __restrict__ out) {
  const int b = blockIdx.x / N_OUT;
  const int o = blockIdx.x % N_OUT;
  float acc = 0.f;
  for (int n = threadIdx.x; n < N_FEAT; n += 256) {
    u64 s = st[N_INPUT + n];
    float w = Wout[(size_t)o * N_FEAT + n];
    acc += ((s >> b) & 1ull) ? w : 0.f;
  }
  for (int off = 32; off > 0; off >>= 1) acc += __shfl_down(acc, off);
  __shared__ float red[4];
  const int wave = threadIdx.x >> 6, lane = threadIdx.x & 63;
  if (lane == 0) red[wave] = acc;
  __syncthreads();
  if (threadIdx.x == 0) {
    float tot = red[0] + red[1] + red[2] + red[3] + bout[o];
    out[(size_t)b * N_OUT + o] = 1.f / (1.f + __expf(-tot));
  }
}

extern "C" void kernel_launch(void* const* d_in, const int* in_sizes, int n_in,
                              void* d_out, int out_size, void* d_ws, size_t ws_size,
                              hipStream_t stream) {
  const int* x    = (const int*)d_in[0];
  const int* w_in = (const int*)d_in[1];
  const int* adj  = (const int*)d_in[2];
  const int* mask = (const int*)d_in[3];
  const int* lut  = (const int*)d_in[4];
  const int* inis = (const int*)d_in[5];
  const float* Wout = (const float*)d_in[6];
  const float* bout = (const float*)d_in[7];
  float* out = (float*)d_out;

  char* ws = (char*)d_ws;
  size_t off = 0;
  auto alloc = [&](size_t bytes) -> void* {
    void* p = ws + off;
    off += (bytes + 255) & ~(size_t)255;
    return p;
  };
  u64* st_all = (u64*)alloc((size_t)T_BUF * ST_WORDS * 8);    // 20.65 MB
  u64* xp     = (u64*)alloc((size_t)T_STEPS * N_BATCH * 8);
  u64* wcol   = (u64*)alloc(64 * 8);
  unsigned* fl = (unsigned*)alloc((size_t)FL_REP * FL_STRIDE * 4);  // 16 KB
  u64* lutp   = (u64*)alloc((size_t)N_NODES * 64 * 8);        // 10.24 MB
  (void)ws_size; (void)in_sizes; (void)n_in; (void)out_size;

  hipLaunchKernelGGL(pack_x_kernel, dim3(T_STEPS), dim3(256), 0, stream, x, xp);
  hipLaunchKernelGGL(pack_lut_fill_kernel, dim3(PL_TOT), dim3(512), 0, stream,
                     lut, inis, lutp, st_all);
  hipLaunchKernelGGL(init_kernel, dim3(2), dim3(256), 0, stream, w_in, wcol, fl);
  hipLaunchKernelGGL(u_pre_kernel, dim3(T_STEPS), dim3(64), 0, stream,
                     xp, wcol, st_all);

  hipLaunchKernelGGL(reservoir_kernel, dim3(NBLK), dim3(NTHR), 0, stream,
                     lutp, adj, mask, st_all, fl);

  // final states live in st[128]
  hipLaunchKernelGGL(readout_kernel, dim3(N_BATCH * N_OUT), dim3(256), 0, stream,
                     st_all + (size_t)T_STEPS * ST_WORDS, Wout, bout, out);
}

// Round 4
// 1003.870 us; speedup vs baseline: 1.2034x; 1.2034x over previous
//
#include <hip/hip_runtime.h>
#include <cstdint>
#include <cstddef>

// BooleanReservoir — persistent kernel, v7.
// lane = batch; states[node] = u64 (bit b = batch b). Packed LUT + adjacency in
// LDS for all 128 steps; cross-block state traffic via agent-scope relaxed
// atomics (L3-coherent).
// R8: exact v4 substrate (best measured: 590 us reservoir / 964 total) with ONE
// barrier variable changed + a cheap readout rewrite:
//   (1) arrival = plain relaxed STORE to own flag fl[bi] (512 contiguous u32),
//       replacing fetch_add on 64 shared counters. Theory: 8 blocks/counter
//       serialized their L3 RMWs (~8 x 700cyc worst case ~= the unexplained
//       ~2 us/step). Leader scans 512 flags with 4 x 64-lane u64 loads; go
//       fan-out (8 lines) unchanged — R3 proved wide polling loses, so only
//       the single leader polls the written lines.
//   (2) readout: 320-block partial kernel (lane=batch, broadcast loads, one
//       cndmask-add per node) + tiny sigmoid kernel. Replaces 640x19936
//       re-read version (~153 MB of L2/L3 traffic).

#define N_NODES   20000
#define N_INPUT   64
#define K_MAX     12
#define T_STEPS   128
#define N_BATCH   64
#define N_OUT     10
#define N_FEAT    (N_NODES - N_INPUT)   // 19936
#define DUMMY_NODE 20000                // always-zero state word
#define ST_WORDS  20004

#define NBLK 512
#define NTHR 512                        // 8 waves/block, 2 blocks/CU
#define NPB  39                         // 512*39 = 19968 >= 19936
#define NPB_PAD 40                      // 8 waves * 5 nodes
#define GO_OFF  512                     // u32 offset of go lines in fl
#define GO_CNT  8
#define GO_STRIDE 32                    // 128 B apart
#define FL_TOT  (GO_OFF + GO_CNT * GO_STRIDE)   // 768 u32

#define RO_CHUNK 32                     // 19936 = 32 * 623
#define RO_NPC   623

typedef unsigned long long u64;

// ---------------- pack x: xp[t][b] = bits j of x[b][t][j] ----------------
__global__ __launch_bounds__(256) void pack_x_kernel(const int* __restrict__ x,
                                                     u64* __restrict__ xp) {
  const int t = blockIdx.x;
  const int wave = threadIdx.x >> 6, lane = threadIdx.x & 63;
  for (int b = wave; b < N_BATCH; b += 4) {
    int v = x[((size_t)b * T_STEPS + t) * 64 + lane];
    u64 bal = __ballot(v != 0);
    if (lane == 0) xp[(size_t)t * N_BATCH + b] = bal;
  }
}

// -------- init state buffers, wcol, u(0), arrival flags + go flags --------
__global__ __launch_bounds__(256) void init_kernel(const int* __restrict__ inis,
                                                   const int* __restrict__ w_in,
                                                   const u64* __restrict__ xp,
                                                   u64* __restrict__ buf0,
                                                   u64* __restrict__ buf1,
                                                   u64* __restrict__ wcol,
                                                   unsigned* __restrict__ fl) {
  if (blockIdx.x < 79) {
    int n = blockIdx.x * 256 + threadIdx.x;
    if (n >= N_INPUT && n < ST_WORDS) {
      u64 w = (n < N_NODES && inis[n] != 0) ? ~0ull : 0ull;   // dummy/pad -> 0
      buf0[n] = w;
      buf1[n] = w;   // no-neigh nodes never rewritten: init lives in both buffers
    }
  } else {
    const int wave = threadIdx.x >> 6, lane = threadIdx.x & 63;
    u64 xw = xp[lane];                       // xp[t=0][b=lane]
    for (int i = wave; i < 64; i += 4) {
      int wv = w_in[(size_t)lane * 64 + i];  // lane = j
      u64 wc = __ballot(wv != 0);
      if (lane == 0) wcol[i] = wc;
      u64 ub = __ballot((xw & wc) != 0);     // u(0)[b][i], lane = b
      if (lane == 0) buf0[i] = ub;
    }
    for (int k = threadIdx.x; k < FL_TOT; k += 256)
      fl[k] = 0u;                            // ws re-poisoned each call
  }
}

// -------- precompute u(t) for all t: u_all[t*64+i] bit b = (xp[t][b].wcol[i]) --------
__global__ __launch_bounds__(64) void u_pre_kernel(const u64* __restrict__ xp,
                                                   const u64* __restrict__ wcol,
                                                   u64* __restrict__ u_all) {
  const int t = blockIdx.x, lane = threadIdx.x;
  u64 xw = xp[(size_t)t * N_BATCH + lane];   // lane = batch
  for (int i = 0; i < 64; i++) {
    u64 ub = __ballot((xw & wcol[i]) != 0);
    if (lane == 0) u_all[(size_t)t * 64 + i] = ub;
  }
}

// ---- 64x64 bit transpose: lane l holds row l; returns lane b holding column b ----
__device__ __forceinline__ u64 bit_transpose64(u64 w, int lane) {
  const u64 LO0 = 0x00000000FFFFFFFFull, LO1 = 0x0000FFFF0000FFFFull,
            LO2 = 0x00FF00FF00FF00FFull, LO3 = 0x0F0F0F0F0F0F0F0Full,
            LO4 = 0x3333333333333333ull, LO5 = 0x5555555555555555ull;
#define XP_STAGE(d, LO)                                                  \
  {                                                                      \
    u64 p = (u64)__shfl_xor((long long)w, (d), 64);                      \
    if (lane & (d)) w = ((p >> (d)) & (LO)) | (w & ~(LO));               \
    else            w = (w & (LO)) | ((p << (d)) & ~(LO));               \
  }
  XP_STAGE(32, LO0) XP_STAGE(16, LO1) XP_STAGE(8, LO2)
  XP_STAGE(4,  LO3) XP_STAGE(2,  LO4) XP_STAGE(1, LO5)
#undef XP_STAGE
  return w;
}

// ---------------- persistent reservoir: all 128 steps ----------------
__global__ __launch_bounds__(NTHR, 4) void reservoir_kernel(
    const int* __restrict__ lut, const int* __restrict__ adj,
    const int* __restrict__ mask, const u64* __restrict__ u_all,
    u64* __restrict__ buf0, u64* __restrict__ buf1,
    unsigned* __restrict__ fl) {
  __shared__ u64 lut_lds[NPB_PAD * 64];        // 20480 B
  __shared__ int adj_lds[NPB_PAD * K_MAX];     //  1920 B
  __shared__ unsigned char hn_lds[NPB_PAD];

  const int bi = blockIdx.x;
  const int tid = threadIdx.x;
  const int wave = tid >> 6, lane = tid & 63;
  const int base = N_INPUT + bi * NPB;
  const int nloc = min(NPB, N_NODES - base);   // last block: 7

  // ---- prologue: adjacency (slot-REVERSED: slot j at offset 11-j) + hn ----
  // After transpose, lane b's bit (12i + (11-j)) = neighbor j -> the 12-bit
  // field (w >> 12i) & 0xFFF is directly the reference's MSB-first LUT index.
  if (tid < NPB_PAD) {
    int i = tid, h = 0;
    if (i < nloc) {
      for (int j = 0; j < K_MAX; j++) {
        int m = mask[(size_t)(base + i) * K_MAX + j];
        int a = adj[(size_t)(base + i) * K_MAX + j];
        adj_lds[i * K_MAX + (K_MAX - 1 - j)] = m ? a : DUMMY_NODE;
        h |= m;
      }
    } else {
      for (int j = 0; j < K_MAX; j++) adj_lds[i * K_MAX + j] = DUMMY_NODE;
    }
    hn_lds[i] = (unsigned char)(h ? 1 : 0);
  }

  // ---- prologue: pack this block's LUT slice into LDS (natural entry order) ----
  const int nwords = nloc * 64;
  const int* lp = lut + (size_t)base * 4096;
  for (int w0 = wave * 8; w0 < nwords; w0 += 64) {
    int v[8];
#pragma unroll
    for (int q = 0; q < 8; q++) {
      int widx = w0 + q;
      v[q] = (widx < nwords) ? lp[(size_t)widx * 64 + lane] : 0;   // coalesced 256B
    }
#pragma unroll
    for (int q = 0; q < 8; q++) {
      int widx = w0 + q;
      u64 bal = __ballot(v[q] != 0);
      if (lane == 0 && widx < nwords) lut_lds[widx] = bal;
    }
  }
  __syncthreads();   // block-local; step 0 reads init_kernel's buf0 (launch-ordered)

  const int l0 = wave * 5;                     // this wave's first local node
  const int cnt = min(5, nloc - l0);           // may be <= 0

  // step-invariant per-wave state (registers):
  int a0 = DUMMY_NODE;                         // lanes 60-63 gather the 0-word
  if (lane < 60) a0 = adj_lds[l0 * K_MAX + lane];
  unsigned hmask = 0;
#pragma unroll
  for (int i = 0; i < 5; i++) hmask |= (unsigned)hn_lds[l0 + i] << i;

  // ---- 128 steps ----
  for (int t = 0; t < T_STEPS; t++) {
    u64* cur = (t & 1) ? buf1 : buf0;
    u64* nxt = (t & 1) ? buf0 : buf1;

    // gather: lane l (<60) -> neighbor word for (node l/12, rev-slot l%12)
    u64 w = __hip_atomic_load(&cur[a0], __ATOMIC_RELAXED, __HIP_MEMORY_SCOPE_AGENT);
    // transpose: lane b now holds all 60 index bits for batch b
    w = bit_transpose64(w, lane);

#pragma unroll
    for (int i = 0; i < 5; i++) {
      if (i < cnt) {                           // wave-uniform
        unsigned idx = (unsigned)(w >> (12 * i)) & 0xFFFu;   // MSB-first index
        u64 g = lut_lds[(l0 + i) * 64 + (idx >> 6)];
        u64 res = __ballot((g >> (idx & 63)) & 1ull);
        if (lane == 0 && ((hmask >> i) & 1u))
          __hip_atomic_store(&nxt[base + l0 + i], res,
                             __ATOMIC_RELAXED, __HIP_MEMORY_SCOPE_AGENT);
      }
    }

    // u(t+1) -> nxt[0..63]: last block's wave 7 (idle there: nloc=7), 64-lane copy
    if (bi == NBLK - 1 && wave == 7 && t + 1 < T_STEPS) {
      u64 uw = u_all[(size_t)(t + 1) * 64 + lane];           // plain coalesced load
      __hip_atomic_store(&nxt[lane], uw, __ATOMIC_RELAXED, __HIP_MEMORY_SCOPE_AGENT);
    }

    // ---- grid barrier: store-flag arrival -> leader scan -> go fan-out ----
    if (t != T_STEPS - 1) {
      const unsigned tgt = (unsigned)(t + 1);
      __syncthreads();   // each wave drains its vmcnt: stores are at L3
      __builtin_amdgcn_fence(__ATOMIC_RELEASE, "workgroup");  // compiler ordering
      if (tid == 0)      // own flag, plain store: NO RMW serialization
        __hip_atomic_store(&fl[bi], tgt, __ATOMIC_RELAXED, __HIP_MEMORY_SCOPE_AGENT);
      if (bi == 0 && wave == 0) {
        // single leader scans all 512 flags: 4 x 64-lane u64 loads per round
        const u64* fp = (const u64*)fl;
        const u64 want = ((u64)tgt << 32) | (u64)tgt;
        for (;;) {
          u64 f0 = __hip_atomic_load(&fp[lane],       __ATOMIC_RELAXED, __HIP_MEMORY_SCOPE_AGENT);
          u64 f1 = __hip_atomic_load(&fp[64 + lane],  __ATOMIC_RELAXED, __HIP_MEMORY_SCOPE_AGENT);
          u64 f2 = __hip_atomic_load(&fp[128 + lane], __ATOMIC_RELAXED, __HIP_MEMORY_SCOPE_AGENT);
          u64 f3 = __hip_atomic_load(&fp[192 + lane], __ATOMIC_RELAXED, __HIP_MEMORY_SCOPE_AGENT);
          bool ok = (f0 == want) && (f1 == want) && (f2 == want) && (f3 == want);
          if (__all(ok)) break;
        }
        if (lane < GO_CNT)
          __hip_atomic_store(&fl[GO_OFF + lane * GO_STRIDE], tgt,
                             __ATOMIC_RELAXED, __HIP_MEMORY_SCOPE_AGENT);
      } else if (wave == 0) {
        // all lanes load the SAME go-flag -> one L3 request per round
        unsigned* gp = &fl[GO_OFF + (bi & (GO_CNT - 1)) * GO_STRIDE];
        while (__hip_atomic_load(gp, __ATOMIC_RELAXED, __HIP_MEMORY_SCOPE_AGENT)
               < tgt) { /* spin */ }
      }
      __builtin_amdgcn_fence(__ATOMIC_ACQUIRE, "workgroup");  // compiler ordering
      __syncthreads();
    }
  }
}

// ---- readout part: partial[c][o][b] = sum over chunk c of W[o][n]*bit(n,b) ----
__global__ __launch_bounds__(256) void readout_part(const u64* __restrict__ st,
                                                    const float* __restrict__ Wout,
                                                    float* __restrict__ partial) {
  const int c = blockIdx.x / N_OUT;            // 0..31
  const int o = blockIdx.x % N_OUT;
  const int b = threadIdx.x & 63, k = threadIdx.x >> 6;   // lane = batch
  const int n0 = c * RO_NPC, n1 = n0 + RO_NPC;
  float acc = 0.f;
  for (int n = n0 + k; n < n1; n += 4) {
    u64 s = st[N_INPUT + n];                   // wave-uniform addr -> broadcast
    float w = Wout[(size_t)o * N_FEAT + n];
    acc += ((s >> b) & 1ull) ? w : 0.f;
  }
  __shared__ float red[4][64];
  red[k][b] = acc;
  __syncthreads();
  if (threadIdx.x < 64) {
    float tot = red[0][b] + red[1][b] + red[2][b] + red[3][b];
    partial[((size_t)c * N_OUT + o) * 64 + b] = tot;
  }
}

// ---- readout final: out[b][o] = sigmoid(sum_c partial + bias) ----
__global__ __launch_bounds__(640) void readout_final(const float* __restrict__ partial,
                                                     const float* __restrict__ bout,
                                                     float* __restrict__ out) {
  const int b = threadIdx.x & 63, o = threadIdx.x >> 6;   // 640 threads
  float tot = bout[o];
  for (int c = 0; c < RO_CHUNK; c++)
    tot += partial[((size_t)c * N_OUT + o) * 64 + b];
  out[(size_t)b * N_OUT + o] = 1.f / (1.f + __expf(-tot));
}

extern "C" void kernel_launch(void* const* d_in, const int* in_sizes, int n_in,
                              void* d_out, int out_size, void* d_ws, size_t ws_size,
                              hipStream_t stream) {
  const int* x    = (const int*)d_in[0];
  const int* w_in = (const int*)d_in[1];
  const int* adj  = (const int*)d_in[2];
  const int* mask = (const int*)d_in[3];
  const int* lut  = (const int*)d_in[4];
  const int* inis = (const int*)d_in[5];
  const float* Wout = (const float*)d_in[6];
  const float* bout = (const float*)d_in[7];
  float* out = (float*)d_out;

  char* ws = (char*)d_ws;
  size_t off = 0;
  auto alloc = [&](size_t bytes) -> void* {
    void* p = ws + off;
    off += (bytes + 255) & ~(size_t)255;
    return p;
  };
  u64* buf0 = (u64*)alloc((size_t)ST_WORDS * 8);
  u64* buf1 = (u64*)alloc((size_t)ST_WORDS * 8);
  u64* xp   = (u64*)alloc((size_t)T_STEPS * N_BATCH * 8);
  u64* wcol = (u64*)alloc(64 * 8);
  u64* u_all = (u64*)alloc((size_t)T_STEPS * 64 * 8);         // 64 KB
  unsigned* fl = (unsigned*)alloc((size_t)FL_TOT * 4);        // 3 KB
  float* partial = (float*)alloc((size_t)RO_CHUNK * N_OUT * 64 * 4);  // 80 KB
  (void)ws_size; (void)in_sizes; (void)n_in; (void)out_size;

  hipLaunchKernelGGL(pack_x_kernel, dim3(T_STEPS), dim3(256), 0, stream, x, xp);
  hipLaunchKernelGGL(init_kernel, dim3(80), dim3(256), 0, stream,
                     inis, w_in, xp, buf0, buf1, wcol, fl);
  hipLaunchKernelGGL(u_pre_kernel, dim3(T_STEPS), dim3(64), 0, stream,
                     xp, wcol, u_all);

  hipLaunchKernelGGL(reservoir_kernel, dim3(NBLK), dim3(NTHR), 0, stream,
                     lut, adj, mask, u_all, buf0, buf1, fl);

  // T even -> final states in buf0
  hipLaunchKernelGGL(readout_part, dim3(RO_CHUNK * N_OUT), dim3(256), 0, stream,
                     buf0, Wout, partial);
  hipLaunchKernelGGL(readout_final, dim3(1), dim3(640), 0, stream,
                     partial, bout, out);
}